// Round 1
// baseline (520592.920 us; speedup 1.0000x reference)
//
#include <hip/hip_runtime.h>
#include <hip/hip_cooperative_groups.h>
#include <cmath>

namespace cg = cooperative_groups;

#define T_STEPS 8192
#define HDIM    2048
#define DIN     128
#define DOUT    128

// ---------------------------------------------------------------------------
// Kernel A: X[t][h] = sum_d inp[t][d] * w_ih[h][d] + b_ih[h]
// C = A * B^T + bias, A:(8192x128) B:(2048x128), tiles 64x64, Kc=64
// ---------------------------------------------------------------------------
__global__ __launch_bounds__(256) void inp_proj_kernel(
    const float* __restrict__ inp, const float* __restrict__ w_ih,
    const float* __restrict__ b_ih, float* __restrict__ X)
{
    __shared__ float As[64][65];
    __shared__ float Bs[64][65];
    const int tid = threadIdx.x;
    const int i0 = blockIdx.x * 64;   // t
    const int j0 = blockIdx.y * 64;   // h
    const int tx = tid % 16, ty = tid / 16;
    float acc[4][4] = {};
    for (int k0 = 0; k0 < DIN; k0 += 64) {
        for (int idx = tid; idx < 64 * 64; idx += 256) {
            int kk = idx % 64, ii = idx / 64;
            As[ii][kk] = inp[(size_t)(i0 + ii) * DIN + k0 + kk];
            Bs[ii][kk] = w_ih[(size_t)(j0 + ii) * DIN + k0 + kk];
        }
        __syncthreads();
        for (int kk = 0; kk < 64; ++kk) {
            float a[4], b[4];
#pragma unroll
            for (int u = 0; u < 4; ++u) a[u] = As[ty * 4 + u][kk];
#pragma unroll
            for (int v = 0; v < 4; ++v) b[v] = Bs[tx * 4 + v][kk];
#pragma unroll
            for (int u = 0; u < 4; ++u)
#pragma unroll
                for (int v = 0; v < 4; ++v) acc[u][v] += a[u] * b[v];
        }
        __syncthreads();
    }
#pragma unroll
    for (int u = 0; u < 4; ++u)
#pragma unroll
        for (int v = 0; v < 4; ++v)
            X[(size_t)(i0 + ty * 4 + u) * HDIM + j0 + tx * 4 + v] =
                acc[u][v] + b_ih[j0 + tx * 4 + v];
}

// ---------------------------------------------------------------------------
// Kernel B: persistent cooperative recurrence.
// 256 blocks x 256 threads. Block b owns rows 8b..8b+7 of W_hh, held in
// registers (32 x float2 per lane). Per step: stage act(8KB) -> LDS, dot,
// 32-lane butterfly reduce, nh = u + dot, X[t] <- nh (in-place over inp_proj),
// act_next <- tanh(nh), grid sync.
// ---------------------------------------------------------------------------
__global__ __launch_bounds__(256, 1) void reservoir_kernel(
    const float* __restrict__ w_hh, float* __restrict__ X,
    float* __restrict__ act_buf)
{
    cg::grid_group grid = cg::this_grid();
    const int b    = blockIdx.x;      // 0..255
    const int tid  = threadIdx.x;     // 0..255
    const int wave = tid >> 6;        // 0..3
    const int lane = tid & 63;
    const int half = lane >> 5;       // 0/1
    const int l32  = lane & 31;
    const int row  = b * 8 + wave * 2 + half;   // global row, 0..2047

    // W slice in registers: cols c = 2*l32 + 64*j + e, j=0..31, e=0..1
    float2 wreg[32];
    {
        const float2* wrow = (const float2*)(w_hh + (size_t)row * HDIM);
#pragma unroll
        for (int j = 0; j < 32; ++j) wreg[j] = wrow[l32 + 32 * j];
    }

    __shared__ float act_lds[HDIM];

    // init act[0] = 0
    if (tid < 8) act_buf[b * 8 + tid] = 0.0f;
    float u_cur = X[row];   // u_0 (X ready: stream-ordered after kernel A)
    __threadfence();
    grid.sync();
    __threadfence();

    for (int t = 0; t < T_STEPS; ++t) {
        const float* act_src = act_buf + (size_t)(t & 1) * HDIM;
        // stage act -> LDS, vectorized
        {
            const float4* s4 = (const float4*)act_src;
            float4* l4 = (float4*)act_lds;
            l4[tid]       = s4[tid];
            l4[tid + 256] = s4[tid + 256];
        }
        __syncthreads();

        // prefetch next u while computing
        float u_next = (t + 1 < T_STEPS) ? X[(size_t)(t + 1) * HDIM + row] : 0.0f;

        const float2* a2 = (const float2*)act_lds;
        float sum = 0.0f;
#pragma unroll
        for (int j = 0; j < 32; ++j) {
            float2 a = a2[l32 + 32 * j];
            sum += wreg[j].x * a.x + wreg[j].y * a.y;
        }
        // butterfly reduce across the 32-lane group
#pragma unroll
        for (int off = 16; off > 0; off >>= 1) sum += __shfl_xor(sum, off, 32);

        float nh = u_cur + sum;
        if (l32 == 0) {
            X[(size_t)t * HDIM + row] = nh;                     // all_hid[t]
            act_buf[(size_t)((t + 1) & 1) * HDIM + row] = tanhf(nh);
        }
        u_cur = u_next;

        __threadfence();
        grid.sync();
        __threadfence();
    }
}

// ---------------------------------------------------------------------------
// Kernel C: C[i][j] = sum_{t=start}^{T-1} A[t][i] * B[t][j]
// A:(T x M), B:(T x N), C:(M x N). Tiles 64x64, Kc=32.
// ---------------------------------------------------------------------------
__global__ __launch_bounds__(256) void atb_kernel(
    const float* __restrict__ A, const float* __restrict__ B,
    float* __restrict__ C, int M, int N, const int* __restrict__ washout_p)
{
    const int w = *washout_p;
    const int start = (T_STEPS > 4 * w) ? w : 0;

    __shared__ float As[32][64];
    __shared__ float Bs[32][64];
    const int tid = threadIdx.x;
    const int i0 = blockIdx.x * 64;
    const int j0 = blockIdx.y * 64;
    const int tx = tid % 16, ty = tid / 16;
    float acc[4][4] = {};

    for (int t0 = start; t0 < T_STEPS; t0 += 32) {
        for (int idx = tid; idx < 32 * 64; idx += 256) {
            int ii = idx % 64, tt = idx / 64;
            int t = t0 + tt;
            As[tt][ii] = (t < T_STEPS) ? A[(size_t)t * M + i0 + ii] : 0.0f;
            Bs[tt][ii] = (t < T_STEPS && (j0 + ii) < N)
                             ? B[(size_t)t * N + j0 + ii] : 0.0f;
        }
        __syncthreads();
        for (int tt = 0; tt < 32; ++tt) {
            float a[4], bb[4];
#pragma unroll
            for (int u = 0; u < 4; ++u) a[u] = As[tt][ty * 4 + u];
#pragma unroll
            for (int v = 0; v < 4; ++v) bb[v] = Bs[tt][tx * 4 + v];
#pragma unroll
            for (int u = 0; u < 4; ++u)
#pragma unroll
                for (int v = 0; v < 4; ++v) acc[u][v] += a[u] * bb[v];
        }
        __syncthreads();
    }
#pragma unroll
    for (int u = 0; u < 4; ++u)
#pragma unroll
        for (int v = 0; v < 4; ++v) {
            int i = i0 + ty * 4 + u, j = j0 + tx * 4 + v;
            if (j < N) C[(size_t)i * N + j] = acc[u][v];
        }
}

// ---------------------------------------------------------------------------
extern "C" void kernel_launch(void* const* d_in, const int* in_sizes, int n_in,
                              void* d_out, int out_size, void* d_ws, size_t ws_size,
                              hipStream_t stream)
{
    const float* inp     = (const float*)d_in[0];   // 8192x128
    const float* target  = (const float*)d_in[1];   // 8192x128
    const float* w_ih    = (const float*)d_in[2];   // 2048x128
    const float* b_ih    = (const float*)d_in[3];   // 2048
    const float* w_hh    = (const float*)d_in[4];   // 2048x2048
    const int*   washout = (const int*)d_in[5];     // scalar

    float* out = (float*)d_out;                  // HTH (2048x2048) ++ HTY (2048x128)
    float* X       = (float*)d_ws;               // 8192x2048 (inp_proj -> all_hid)
    float* act_buf = X + (size_t)T_STEPS * HDIM; // 2x2048

    // A: inp_proj
    inp_proj_kernel<<<dim3(T_STEPS / 64, HDIM / 64), dim3(256), 0, stream>>>(
        inp, w_ih, b_ih, X);

    // B: recurrence (cooperative: grid-wide sync per step)
    {
        const float* whh_p = w_hh;
        float* X_p = X;
        float* act_p = act_buf;
        void* kargs[] = { (void*)&whh_p, (void*)&X_p, (void*)&act_p };
        hipLaunchCooperativeKernel((const void*)reservoir_kernel, dim3(256),
                                   dim3(256), kargs, 0, stream);
    }

    // C: HTH = X[w:]^T X[w:]  (2048x2048)
    atb_kernel<<<dim3(HDIM / 64, HDIM / 64), dim3(256), 0, stream>>>(
        X, X, out, HDIM, HDIM, washout);
    // C: HTY = X[w:]^T Y[w:]  (2048x128)
    atb_kernel<<<dim3(HDIM / 64, DOUT / 64), dim3(256), 0, stream>>>(
        X, target, out + (size_t)HDIM * HDIM, HDIM, DOUT, washout);
}

// Round 2
// 35477.359 us; speedup vs baseline: 14.6739x; 14.6739x over previous
//
#include <hip/hip_runtime.h>
#include <cmath>

#define T_STEPS 8192
#define HDIM    2048
#define DIN     128
#define DOUT    128
#define NB      64          // reservoir blocks
#define BT      1024        // threads per reservoir block
#define RPB     (HDIM / NB) // 32 rows per block

__device__ __forceinline__ float agent_load(const float* p) {
    return __hip_atomic_load(p, __ATOMIC_RELAXED, __HIP_MEMORY_SCOPE_AGENT);
}
__device__ __forceinline__ void agent_store(float* p, float v) {
    __hip_atomic_store(p, v, __ATOMIC_RELAXED, __HIP_MEMORY_SCOPE_AGENT);
}

// ---------------------------------------------------------------------------
// Prefill: seed act slot1 = +3 (encoded act_{-1}=0, epoch e=1), slot0 = 0
// (neutral: not accepted by any epoch predicate). Runs every call ->
// deterministic across graph replays.
// ---------------------------------------------------------------------------
__global__ void prefill_kernel(float* __restrict__ act_buf) {
    int i = blockIdx.x * blockDim.x + threadIdx.x;
    if (i < HDIM) {
        act_buf[i]        = 0.0f;   // slot 0
        act_buf[HDIM + i] = 3.0f;   // slot 1: 0 + 3
    }
}

// ---------------------------------------------------------------------------
// Kernel A: X[t][h] = sum_d inp[t][d] * w_ih[h][d] + b_ih[h]
// ---------------------------------------------------------------------------
__global__ __launch_bounds__(256) void inp_proj_kernel(
    const float* __restrict__ inp, const float* __restrict__ w_ih,
    const float* __restrict__ b_ih, float* __restrict__ X)
{
    __shared__ float As[64][65];
    __shared__ float Bs[64][65];
    const int tid = threadIdx.x;
    const int i0 = blockIdx.x * 64;   // t
    const int j0 = blockIdx.y * 64;   // h
    const int tx = tid % 16, ty = tid / 16;
    float acc[4][4] = {};
    for (int k0 = 0; k0 < DIN; k0 += 64) {
        for (int idx = tid; idx < 64 * 64; idx += 256) {
            int kk = idx % 64, ii = idx / 64;
            As[ii][kk] = inp[(size_t)(i0 + ii) * DIN + k0 + kk];
            Bs[ii][kk] = w_ih[(size_t)(j0 + ii) * DIN + k0 + kk];
        }
        __syncthreads();
        for (int kk = 0; kk < 64; ++kk) {
            float a[4], b[4];
#pragma unroll
            for (int u = 0; u < 4; ++u) a[u] = As[ty * 4 + u][kk];
#pragma unroll
            for (int v = 0; v < 4; ++v) b[v] = Bs[tx * 4 + v][kk];
#pragma unroll
            for (int u = 0; u < 4; ++u)
#pragma unroll
                for (int v = 0; v < 4; ++v) acc[u][v] += a[u] * b[v];
        }
        __syncthreads();
    }
#pragma unroll
    for (int u = 0; u < 4; ++u)
#pragma unroll
        for (int v = 0; v < 4; ++v)
            X[(size_t)(i0 + ty * 4 + u) * HDIM + j0 + tx * 4 + v] =
                acc[u][v] + b_ih[j0 + tx * 4 + v];
}

// ---------------------------------------------------------------------------
// Kernel B: reservoir recurrence, NO grid barrier, NO fences.
// 64 blocks x 1024 threads. Block b owns rows b*32..b*32+31; wave w handles
// rows b*32 + 2w + {0,1} (one per 32-lane half). W slice in 64 VGPRs/thread:
// wreg[j] = W[row][32j + l32].
// act published as agent-scope atomics, epoch-encoded: stored = tanh(nh) +
// (((t>>1)&1) ? +3 : -3) into slot t&1. Consumers spin until the value is in
// the expected epoch half-range. Data IS the flag.
// Overwrite safety: block writes slot t&1 (killing act_{t-2}) only after its
// spin observed ALL of act_{t-1}; any block that published act_{t-1} had
// already finished its global reads of act_{t-2} (they precede its
// __syncthreads, which precedes its publish).
// ---------------------------------------------------------------------------
__global__ __launch_bounds__(BT, 1) void reservoir_kernel(
    const float* __restrict__ w_hh, float* __restrict__ X,
    float* __restrict__ act_buf)
{
    const int b    = blockIdx.x;
    const int tid  = threadIdx.x;
    const int wave = tid >> 6;
    const int lane = tid & 63;
    const int half = lane >> 5;
    const int l32  = lane & 31;
    const int row  = b * RPB + wave * 2 + half;

    // W slice: wreg[j] = W[row][32j + l32]  (coalesced 128B per half-wave)
    float wreg[64];
    {
        const float* wrow = w_hh + (size_t)row * HDIM;
#pragma unroll
        for (int j = 0; j < 64; ++j) wreg[j] = wrow[j * 32 + l32];
    }

    __shared__ float lds[2][HDIM];

    float u_cur = X[row];   // u_0 (inp_proj is stream-ordered before us)

    for (int t = 0; t < T_STEPS; ++t) {
        // consume act_{t-1}: slot (t-1)&1 == (t+1)&1, epoch ((t-1)>>1)&1 == ((t+3)>>1)&1
        const int   s   = (t + 1) & 1;
        const int   e   = ((t + 3) >> 1) & 1;
        const float off = e ? 3.0f : -3.0f;
        float* src = act_buf + s * HDIM;

        const int i0 = tid * 2;
        float x0, x1;
        bool  r0 = false, r1 = false;
        do {
            if (!r0) { x0 = agent_load(src + i0);     r0 = e ? (x0 >= 2.0f) : (x0 <= -2.0f); }
            if (!r1) { x1 = agent_load(src + i0 + 1); r1 = e ? (x1 >= 2.0f) : (x1 <= -2.0f); }
        } while (!(r0 && r1));

        const int ls = t & 1;
        lds[ls][i0]     = x0 - off;
        lds[ls][i0 + 1] = x1 - off;
        __syncthreads();

        // dot: row ⋅ act, 64 FMAs, LDS reads conflict-free (32 consecutive
        // floats per j, broadcast across the two halves)
        const float* a = lds[ls];
        float sum = 0.0f, sum2 = 0.0f;
#pragma unroll
        for (int j = 0; j < 64; j += 2) {
            sum  += wreg[j]     * a[j * 32 + l32];
            sum2 += wreg[j + 1] * a[(j + 1) * 32 + l32];
        }
        sum += sum2;
#pragma unroll
        for (int o = 16; o > 0; o >>= 1) sum += __shfl_xor(sum, o, 32);

        if (l32 == 0) {
            float nh = u_cur + sum;
            X[(size_t)t * HDIM + row] = nh;               // all_hid[t] (in-place over u)
            float na = tanhf(nh);
            const float poff = ((t >> 1) & 1) ? 3.0f : -3.0f;
            agent_store(act_buf + (t & 1) * HDIM + row, na + poff);
            if (t + 1 < T_STEPS)
                u_cur = X[(size_t)(t + 1) * HDIM + row];  // prefetch next u
        }
    }
}

// ---------------------------------------------------------------------------
// Kernel C: C[i][j] = sum_{t=start}^{T-1} A[t][i] * B[t][j]
// ---------------------------------------------------------------------------
__global__ __launch_bounds__(256) void atb_kernel(
    const float* __restrict__ A, const float* __restrict__ B,
    float* __restrict__ C, int M, int N, const int* __restrict__ washout_p)
{
    const int w = *washout_p;
    const int start = (T_STEPS > 4 * w) ? w : 0;

    __shared__ float As[32][64];
    __shared__ float Bs[32][64];
    const int tid = threadIdx.x;
    const int i0 = blockIdx.x * 64;
    const int j0 = blockIdx.y * 64;
    const int tx = tid % 16, ty = tid / 16;
    float acc[4][4] = {};

    for (int t0 = start; t0 < T_STEPS; t0 += 32) {
        for (int idx = tid; idx < 32 * 64; idx += 256) {
            int ii = idx % 64, tt = idx / 64;
            int t = t0 + tt;
            As[tt][ii] = (t < T_STEPS) ? A[(size_t)t * M + i0 + ii] : 0.0f;
            Bs[tt][ii] = (t < T_STEPS && (j0 + ii) < N)
                             ? B[(size_t)t * N + j0 + ii] : 0.0f;
        }
        __syncthreads();
        for (int tt = 0; tt < 32; ++tt) {
            float a[4], bb[4];
#pragma unroll
            for (int u = 0; u < 4; ++u) a[u] = As[tt][ty * 4 + u];
#pragma unroll
            for (int v = 0; v < 4; ++v) bb[v] = Bs[tt][tx * 4 + v];
#pragma unroll
            for (int u = 0; u < 4; ++u)
#pragma unroll
                for (int v = 0; v < 4; ++v) acc[u][v] += a[u] * bb[v];
        }
        __syncthreads();
    }
#pragma unroll
    for (int u = 0; u < 4; ++u)
#pragma unroll
        for (int v = 0; v < 4; ++v) {
            int i = i0 + ty * 4 + u, j = j0 + tx * 4 + v;
            if (j < N) C[(size_t)i * N + j] = acc[u][v];
        }
}

// ---------------------------------------------------------------------------
extern "C" void kernel_launch(void* const* d_in, const int* in_sizes, int n_in,
                              void* d_out, int out_size, void* d_ws, size_t ws_size,
                              hipStream_t stream)
{
    const float* inp     = (const float*)d_in[0];   // 8192x128
    const float* target  = (const float*)d_in[1];   // 8192x128
    const float* w_ih    = (const float*)d_in[2];   // 2048x128
    const float* b_ih    = (const float*)d_in[3];   // 2048
    const float* w_hh    = (const float*)d_in[4];   // 2048x2048
    const int*   washout = (const int*)d_in[5];     // scalar

    float* out = (float*)d_out;                  // HTH (2048x2048) ++ HTY (2048x128)
    float* X       = (float*)d_ws;               // 8192x2048 (inp_proj -> all_hid)
    float* act_buf = X + (size_t)T_STEPS * HDIM; // 2x2048

    prefill_kernel<<<dim3(8), dim3(256), 0, stream>>>(act_buf);

    inp_proj_kernel<<<dim3(T_STEPS / 64, HDIM / 64), dim3(256), 0, stream>>>(
        inp, w_ih, b_ih, X);

    {
        const float* whh_p = w_hh;
        float* X_p = X;
        float* act_p = act_buf;
        void* kargs[] = { (void*)&whh_p, (void*)&X_p, (void*)&act_p };
        hipLaunchCooperativeKernel((const void*)reservoir_kernel, dim3(NB),
                                   dim3(BT), kargs, 0, stream);
    }

    atb_kernel<<<dim3(HDIM / 64, HDIM / 64), dim3(256), 0, stream>>>(
        X, X, out, HDIM, HDIM, washout);
    atb_kernel<<<dim3(HDIM / 64, DOUT / 64), dim3(256), 0, stream>>>(
        X, target, out + (size_t)HDIM * HDIM, HDIM, DOUT, washout);
}

// Round 3
// 23165.700 us; speedup vs baseline: 22.4726x; 1.5315x over previous
//
#include <hip/hip_runtime.h>
#include <cmath>
#include <cstring>

#define T_STEPS 8192
#define HDIM    2048
#define DIN     128
#define DOUT    128
#define NB      64          // reservoir blocks (32 rows each)
#define BT      512         // threads per reservoir block

__device__ __forceinline__ unsigned long long agent_load8(const unsigned long long* p) {
    return __hip_atomic_load(p, __ATOMIC_RELAXED, __HIP_MEMORY_SCOPE_AGENT);
}
__device__ __forceinline__ void agent_store8(unsigned long long* p, unsigned long long v) {
    __hip_atomic_store(p, v, __ATOMIC_RELAXED, __HIP_MEMORY_SCOPE_AGENT);
}

// ---------------------------------------------------------------------------
// Prefill: slot1 = +3 (encoded act_{-1}=0, epoch 1), slot0 = 0 (neutral).
// Runs every call -> deterministic across graph replays.
// ---------------------------------------------------------------------------
__global__ void prefill_kernel(float* __restrict__ act_buf) {
    int i = blockIdx.x * blockDim.x + threadIdx.x;
    if (i < HDIM) {
        act_buf[i]        = 0.0f;
        act_buf[HDIM + i] = 3.0f;
    }
}

// ---------------------------------------------------------------------------
// Kernel A: X[t][h] = sum_d inp[t][d] * w_ih[h][d] + b_ih[h]
// ---------------------------------------------------------------------------
__global__ __launch_bounds__(256) void inp_proj_kernel(
    const float* __restrict__ inp, const float* __restrict__ w_ih,
    const float* __restrict__ b_ih, float* __restrict__ X)
{
    __shared__ float As[64][65];
    __shared__ float Bs[64][65];
    const int tid = threadIdx.x;
    const int i0 = blockIdx.x * 64;   // t
    const int j0 = blockIdx.y * 64;   // h
    const int tx = tid % 16, ty = tid / 16;
    float acc[4][4] = {};
    for (int k0 = 0; k0 < DIN; k0 += 64) {
        for (int idx = tid; idx < 64 * 64; idx += 256) {
            int kk = idx % 64, ii = idx / 64;
            As[ii][kk] = inp[(size_t)(i0 + ii) * DIN + k0 + kk];
            Bs[ii][kk] = w_ih[(size_t)(j0 + ii) * DIN + k0 + kk];
        }
        __syncthreads();
        for (int kk = 0; kk < 64; ++kk) {
            float a[4], b[4];
#pragma unroll
            for (int u = 0; u < 4; ++u) a[u] = As[ty * 4 + u][kk];
#pragma unroll
            for (int v = 0; v < 4; ++v) b[v] = Bs[tx * 4 + v][kk];
#pragma unroll
            for (int u = 0; u < 4; ++u)
#pragma unroll
                for (int v = 0; v < 4; ++v) acc[u][v] += a[u] * b[v];
        }
        __syncthreads();
    }
#pragma unroll
    for (int u = 0; u < 4; ++u)
#pragma unroll
        for (int v = 0; v < 4; ++v)
            X[(size_t)(i0 + ty * 4 + u) * HDIM + j0 + tx * 4 + v] =
                acc[u][v] + b_ih[j0 + tx * 4 + v];
}

// ---------------------------------------------------------------------------
// Kernel B: reservoir recurrence. 64 blocks x 512 threads.
// Group g = (wave*2 + half) of 32 lanes owns rows r0=b*32+2g, r0+1.
// W slice pinned in VGPRs (asm barrier prevents rematerialization):
//   w0[j],w1[j] = W[r0 / r0+1][2*l32 + 64*j + {0,1}]  (128 VGPRs)
// Per step: 8B epoch-encoded atomic polls (data IS the flag), float2 LDS
// staging, 32x ds_read_b64 dot feeding 4 FMAs each, dual butterfly reduce,
// float2 publish. Same epoch/slot protocol as R2 (proven).
// ---------------------------------------------------------------------------
__global__ __launch_bounds__(BT, 1) void reservoir_kernel(
    const float* __restrict__ w_hh, float* __restrict__ X,
    float* __restrict__ act_buf)
{
    const int b    = blockIdx.x;
    const int tid  = threadIdx.x;
    const int wave = tid >> 6;
    const int lane = tid & 63;
    const int half = lane >> 5;
    const int l32  = lane & 31;
    const int grp  = wave * 2 + half;     // 0..15
    const int r0   = b * 32 + grp * 2;    // even row; pair (r0, r0+1)

    float2 w0[32], w1[32];
    {
        const float2* p0 = (const float2*)(w_hh + (size_t)r0 * HDIM);
        const float2* p1 = (const float2*)(w_hh + (size_t)(r0 + 1) * HDIM);
#pragma unroll
        for (int j = 0; j < 32; ++j) {
            w0[j] = p0[l32 + 32 * j];
            w1[j] = p1[l32 + 32 * j];
        }
    }
#pragma unroll
    for (int j = 0; j < 32; ++j) {
        asm volatile("" : "+v"(w0[j].x), "+v"(w0[j].y),
                          "+v"(w1[j].x), "+v"(w1[j].y));
    }

    __shared__ float2 lds[2][HDIM / 2];

    const int p0i = tid, p1i = tid + BT;   // float2 indices this thread polls

    float2 u_cur = make_float2(0.0f, 0.0f);
    if (l32 == 0) u_cur = *(const float2*)(X + r0);   // u_0

    for (int t = 0; t < T_STEPS; ++t) {
        // consume act_{t-1}: slot (t+1)&1, epoch ((t+3)>>1)&1
        const int   s   = (t + 1) & 1;
        const int   e   = ((t + 3) >> 1) & 1;
        const float off = e ? 3.0f : -3.0f;
        const unsigned long long* src =
            (const unsigned long long*)(act_buf + (size_t)s * HDIM);

        unsigned long long v0, v1;
        bool q0 = false, q1 = false;
        do {
            if (!q0) {
                v0 = agent_load8(src + p0i);
                float2 f; memcpy(&f, &v0, 8);
                q0 = e ? (f.x >= 2.0f && f.y >= 2.0f)
                       : (f.x <= -2.0f && f.y <= -2.0f);
            }
            if (!q1) {
                v1 = agent_load8(src + p1i);
                float2 f; memcpy(&f, &v1, 8);
                q1 = e ? (f.x >= 2.0f && f.y >= 2.0f)
                       : (f.x <= -2.0f && f.y <= -2.0f);
            }
        } while (!(q0 && q1));

        const int ls = t & 1;
        {
            float2 f0, f1; memcpy(&f0, &v0, 8); memcpy(&f1, &v1, 8);
            f0.x -= off; f0.y -= off; f1.x -= off; f1.y -= off;
            lds[ls][p0i] = f0;
            lds[ls][p1i] = f1;
        }
        __syncthreads();

        // prefetch next u (hidden under the dot)
        float2 u_next = make_float2(0.0f, 0.0f);
        if (l32 == 0 && t + 1 < T_STEPS)
            u_next = *(const float2*)(X + (size_t)(t + 1) * HDIM + r0);

        const float2* a = lds[ls];
        float s0 = 0.0f, s1 = 0.0f;
#pragma unroll
        for (int j = 0; j < 32; ++j) {
            float2 av = a[l32 + 32 * j];
            s0 += w0[j].x * av.x + w0[j].y * av.y;
            s1 += w1[j].x * av.x + w1[j].y * av.y;
        }
#pragma unroll
        for (int o = 16; o > 0; o >>= 1) {
            s0 += __shfl_xor(s0, o, 32);
            s1 += __shfl_xor(s1, o, 32);
        }

        if (l32 == 0) {
            float nh0 = u_cur.x + s0;
            float nh1 = u_cur.y + s1;
            *(float2*)(X + (size_t)t * HDIM + r0) = make_float2(nh0, nh1);
            const float poff = ((t >> 1) & 1) ? 3.0f : -3.0f;
            float2 na = make_float2(tanhf(nh0) + poff, tanhf(nh1) + poff);
            unsigned long long pv; memcpy(&pv, &na, 8);
            agent_store8((unsigned long long*)(act_buf + (size_t)(t & 1) * HDIM)
                             + (b * 16 + grp), pv);
            u_cur = u_next;
        }
    }
}

// ---------------------------------------------------------------------------
// Kernel C: C[i][j] = sum_{t=start}^{T-1} A[t][i] * B[t][j]
// ---------------------------------------------------------------------------
__global__ __launch_bounds__(256) void atb_kernel(
    const float* __restrict__ A, const float* __restrict__ B,
    float* __restrict__ C, int M, int N, const int* __restrict__ washout_p)
{
    const int w = *washout_p;
    const int start = (T_STEPS > 4 * w) ? w : 0;

    __shared__ float As[32][64];
    __shared__ float Bs[32][64];
    const int tid = threadIdx.x;
    const int i0 = blockIdx.x * 64;
    const int j0 = blockIdx.y * 64;
    const int tx = tid % 16, ty = tid / 16;
    float acc[4][4] = {};

    for (int t0 = start; t0 < T_STEPS; t0 += 32) {
        for (int idx = tid; idx < 32 * 64; idx += 256) {
            int ii = idx % 64, tt = idx / 64;
            int t = t0 + tt;
            As[tt][ii] = (t < T_STEPS) ? A[(size_t)t * M + i0 + ii] : 0.0f;
            Bs[tt][ii] = (t < T_STEPS && (j0 + ii) < N)
                             ? B[(size_t)t * N + j0 + ii] : 0.0f;
        }
        __syncthreads();
        for (int tt = 0; tt < 32; ++tt) {
            float a[4], bb[4];
#pragma unroll
            for (int u = 0; u < 4; ++u) a[u] = As[tt][ty * 4 + u];
#pragma unroll
            for (int v = 0; v < 4; ++v) bb[v] = Bs[tt][tx * 4 + v];
#pragma unroll
            for (int u = 0; u < 4; ++u)
#pragma unroll
                for (int v = 0; v < 4; ++v) acc[u][v] += a[u] * bb[v];
        }
        __syncthreads();
    }
#pragma unroll
    for (int u = 0; u < 4; ++u)
#pragma unroll
        for (int v = 0; v < 4; ++v) {
            int i = i0 + ty * 4 + u, j = j0 + tx * 4 + v;
            if (j < N) C[(size_t)i * N + j] = acc[u][v];
        }
}

// ---------------------------------------------------------------------------
extern "C" void kernel_launch(void* const* d_in, const int* in_sizes, int n_in,
                              void* d_out, int out_size, void* d_ws, size_t ws_size,
                              hipStream_t stream)
{
    const float* inp     = (const float*)d_in[0];   // 8192x128
    const float* target  = (const float*)d_in[1];   // 8192x128
    const float* w_ih    = (const float*)d_in[2];   // 2048x128
    const float* b_ih    = (const float*)d_in[3];   // 2048
    const float* w_hh    = (const float*)d_in[4];   // 2048x2048
    const int*   washout = (const int*)d_in[5];     // scalar

    float* out = (float*)d_out;                  // HTH (2048x2048) ++ HTY (2048x128)
    float* X       = (float*)d_ws;               // 8192x2048 (inp_proj -> all_hid)
    float* act_buf = X + (size_t)T_STEPS * HDIM; // 2x2048

    prefill_kernel<<<dim3(8), dim3(256), 0, stream>>>(act_buf);

    inp_proj_kernel<<<dim3(T_STEPS / 64, HDIM / 64), dim3(256), 0, stream>>>(
        inp, w_ih, b_ih, X);

    reservoir_kernel<<<dim3(NB), dim3(BT), 0, stream>>>(w_hh, X, act_buf);

    atb_kernel<<<dim3(HDIM / 64, HDIM / 64), dim3(256), 0, stream>>>(
        X, X, out, HDIM, HDIM, washout);
    atb_kernel<<<dim3(HDIM / 64, DOUT / 64), dim3(256), 0, stream>>>(
        X, target, out + (size_t)HDIM * HDIM, HDIM, DOUT, washout);
}